// Round 11
// baseline (288.532 us; speedup 1.0000x reference)
//
#include <hip/hip_runtime.h>

#define NN 10242

typedef short s8v __attribute__((ext_vector_type(8)));
typedef float f32x4 __attribute__((ext_vector_type(4)));

static __device__ __forceinline__ float bf2f(unsigned short u) {
    unsigned int i = ((unsigned int)u) << 16;
    return __builtin_bit_cast(float, i);
}
static __device__ __forceinline__ unsigned short f2bf(float f) {
    unsigned int i = __builtin_bit_cast(unsigned int, f);
    unsigned int lsb = (i >> 16) & 1u;
    i += 0x7fffu + lsb;
    return (unsigned short)(i >> 16);
}
static __device__ __forceinline__ int imin(int a, int b) { return a < b ? a : b; }

// ---- dtype detector: neigh_weights rows (triples) sum to 1 in the true dtype ----
__global__ void detect_k(const void* __restrict__ wgt, int* __restrict__ flag) {
    const float* wf = (const float*)wgt;
    const int r = threadIdx.x;
    float s = wf[3 * r] + wf[3 * r + 1] + wf[3 * r + 2];
    bool ok = (s == s) && (fabsf(s - 1.f) < 0.05f);
    unsigned long long m = __ballot(ok);
    if (r == 0) *flag = (__popcll(m) >= 60) ? 1 : 0;
}

// ---- canonicalizer ----
// mode 0: ->bf16   mode 1: ->f32   mode 2: W1 cols 75->80 ->bf16
// mode 4: W[cout][25*cin] -> Bt[cin/8][cpadA][8] bf16 where column ncol=k*coutp+c
struct Seg { const void* src; void* dst; int n; int nsrc; int mode; int K; int cout; int cpad; int coutp; };
struct Tab { Seg s[16]; };

__global__ __launch_bounds__(256) void canon_k(Tab t, const int* __restrict__ flag) {
    const Seg sg = t.s[blockIdx.y];
    const bool f32src = (*flag != 0);
    for (int i = blockIdx.x * 256 + threadIdx.x; i < sg.n; i += gridDim.x * 256) {
        if (sg.mode == 0) {
            unsigned short v = 0;
            if (i < sg.nsrc)
                v = f32src ? f2bf(((const float*)sg.src)[i])
                           : ((const unsigned short*)sg.src)[i];
            ((unsigned short*)sg.dst)[i] = v;
        } else if (sg.mode == 1) {
            float v = f32src ? ((const float*)sg.src)[i]
                             : bf2f(((const unsigned short*)sg.src)[i]);
            ((float*)sg.dst)[i] = v;
        } else if (sg.mode == 2) {
            const int row = i / 80, col = i - row * 80;
            unsigned short v = 0;
            if (col < 75) {
                const int j = row * 75 + col;
                v = f32src ? f2bf(((const float*)sg.src)[j])
                           : ((const unsigned short*)sg.src)[j];
            }
            ((unsigned short*)sg.dst)[i] = v;
        } else {
            const int e = i & 7;
            const int r = i >> 3;
            const int ncol = r % sg.cpad;
            const int k8 = r / sg.cpad;
            const int cin = sg.K / 25;
            const int k = ncol / sg.coutp;
            const int c = ncol - k * sg.coutp;
            const int ck = k8 * 8 + e;
            unsigned short v = 0;
            if (k < 25 && c < sg.cout && ck < cin) {
                const int j = c * sg.K + k * cin + ck;
                v = f32src ? f2bf(((const float*)sg.src)[j])
                           : ((const unsigned short*)sg.src)[j];
            }
            ((unsigned short*)sg.dst)[i] = v;
        }
    }
}

// ---- layer-1 conv (K=80, VALU; cheap, proven) ----
template<int CIN, int COUT, int CG, int NB>
__global__ __launch_bounds__(256) void conv_k(
    const unsigned short* __restrict__ X,
    const int* __restrict__ idx,
    const float* __restrict__ wgt,
    const unsigned short* __restrict__ W,    // [COUT][KPAD]
    const float* __restrict__ bias,
    float* __restrict__ Of)
{
    constexpr int K = 25 * CIN;
    constexpr int KPAD = (K + 7) & ~7;
    __shared__ unsigned short agg[NB][KPAD];
    const int tid = threadIdx.x;
    const int n0 = blockIdx.x * NB;

    for (int p = tid; p < NB * 25; p += 256) {
        const int r = p / 25;
        const int k = p - r * 25;
        const int n = n0 + r;
        if (n < NN) {
            const int base = n * 75 + k * 3;
            const int i0 = idx[base], i1 = idx[base + 1], i2 = idx[base + 2];
            const float w0 = wgt[base], w1 = wgt[base + 1], w2 = wgt[base + 2];
            for (int e = 0; e < CIN; e++) {
                float v = w0 * bf2f(X[i0 * CIN + e]) +
                          w1 * bf2f(X[i1 * CIN + e]) +
                          w2 * bf2f(X[i2 * CIN + e]);
                agg[r][k * CIN + e] = f2bf(v);
            }
        } else {
            for (int e = 0; e < CIN; e++) agg[r][k * CIN + e] = 0;
        }
    }
    if constexpr (KPAD != K) {
        for (int p = tid; p < NB * (KPAD - K); p += 256) {
            const int r = p / (KPAD - K);
            agg[r][K + p - r * (KPAD - K)] = 0;
        }
    }
    __syncthreads();

    constexpr int RG = 256 / CG;
    constexpr int RPT = NB / RG;
    const int c = tid % CG;
    const int rq = tid / CG;
    float acc[RPT] = {};
    if (c < COUT) {
        const unsigned short* Wr = W + (size_t)c * KPAD;
        for (int j = 0; j < KPAD; j += 8) {
            s8v wv = *(const s8v*)(Wr + j);
            float wf[8];
            #pragma unroll
            for (int q = 0; q < 8; q++) wf[q] = bf2f((unsigned short)wv[q]);
            #pragma unroll
            for (int rr = 0; rr < RPT; rr++) {
                s8v av = *(const s8v*)(&agg[rq * RPT + rr][j]);
                #pragma unroll
                for (int q = 0; q < 8; q++)
                    acc[rr] += wf[q] * bf2f((unsigned short)av[q]);
            }
        }
        const float bb = bias[c];
        #pragma unroll
        for (int rr = 0; rr < RPT; rr++) {
            const int n = n0 + rq * RPT + rr;
            if (n < NN) Of[(size_t)n * COUT + c] = acc[rr] + bb;
        }
    }
}

// ---- dense GEMM: Y[m, k*COUTP+c] = X[m,:] . W[c, k*CIN:+CIN]  (no gathers) ----
// Block: 64 rows x 256 cols; 4 waves each 16 rows x 256 cols (NFRAG=16).
template<int CIN, int NCOL, int CPADA>
__global__ __launch_bounds__(256) void gemmy_k(
    const unsigned short* __restrict__ X,    // [NN][CIN] bf16
    const unsigned short* __restrict__ Bt,   // [CIN/8][CPADA][8] bf16
    unsigned short* __restrict__ Y)          // [NN][NCOL] bf16
{
    constexpr int NT = CIN / 32;
    constexpr int NFRAG = 16;
    constexpr int LW = CIN + 8;
    constexpr int CH8 = CIN / 8;
    __shared__ unsigned short lds[64][LW];
    const int tid = threadIdx.x;
    const int m0 = blockIdx.x * 64;
    const int colblk = blockIdx.y * 256;

    for (int q = tid; q < 64 * CH8; q += 256) {
        const int r = q / CH8, cc = q - r * CH8;
        const int m = m0 + r;
        s8v v = { 0, 0, 0, 0, 0, 0, 0, 0 };
        if (m < NN) v = *(const s8v*)(X + (size_t)m * CIN + cc * 8);
        *(s8v*)(&lds[r][cc * 8]) = v;
    }
    __syncthreads();

    const int wv = tid >> 6, lane = tid & 63;
    const int l15 = lane & 15, kg = lane >> 4;
    const int row0 = wv * 16;
    f32x4 acc[NFRAG] = {};
    #pragma unroll
    for (int t = 0; t < NT; t++) {
        const s8v a = *(const s8v*)(&lds[row0 + l15][t * 32 + kg * 8]);
        const int k8 = t * 4 + kg;
        const unsigned short* wp = Bt + ((size_t)k8 * CPADA + colblk + l15) * 8;
        #pragma unroll
        for (int j = 0; j < NFRAG; j++) {
            const s8v b = *(const s8v*)(wp + j * 16 * 8);
            acc[j] = __builtin_amdgcn_mfma_f32_16x16x32_bf16(a, b, acc[j], 0, 0, 0);
        }
    }
    #pragma unroll
    for (int j = 0; j < NFRAG; j++) {
        const int col = colblk + j * 16 + l15;
        if (col < NCOL) {
            #pragma unroll
            for (int q = 0; q < 4; q++) {
                const int m = m0 + row0 + kg * 4 + q;   // C row = (lane>>4)*4 + reg
                if (m < NN) Y[(size_t)m * NCOL + col] = f2bf(acc[j][q]);
            }
        }
    }
}

// ---- streaming combine: out[n,c] = bias[c] + sum_{k,t} w[n,k,t] * Y[idx[n,k,t], k, c] ----
// WPN waves per node (WPN=2 for COUTP=128); lane = channel; 75 coalesced row-seg reads/node.
template<int COUTP, int COUT, int WPN, bool FINAL>
__global__ __launch_bounds__(256) void comb_k(
    const unsigned short* __restrict__ Y,
    const int* __restrict__ idx,
    const float* __restrict__ wgt,
    const float* __restrict__ bias,
    float* __restrict__ pre,
    void* __restrict__ Ob,
    const int* __restrict__ flag)
{
    constexpr int NPB = 4 / WPN;
    __shared__ int   iL[NPB * 75];
    __shared__ float wL[NPB * 75];
    const int tid = threadIdx.x;
    const int nblk = blockIdx.x * NPB;

    for (int q = tid; q < NPB * 75; q += 256) {
        const int nl = q / 75;
        const int n = nblk + nl;
        const bool ok = n < NN;
        const int g = ok ? (n * 75 + (q - nl * 75)) : 0;
        iL[q] = ok ? idx[g] : 0;
        wL[q] = ok ? wgt[g] : 0.f;
    }
    __syncthreads();

    const int wv = tid >> 6;
    const int lane = tid & 63;
    const int nl = wv / WPN;
    const int n = nblk + nl;
    const int ch = (wv % WPN) * 64 + lane;
    if (n >= NN || ch >= COUTP) return;

    float a0 = 0.f, a1 = 0.f, a2 = 0.f;
    const int ib = nl * 75;
    #pragma unroll
    for (int k = 0; k < 25; k++) {
        const int i0 = iL[ib + k * 3], i1 = iL[ib + k * 3 + 1], i2 = iL[ib + k * 3 + 2];
        const float w0 = wL[ib + k * 3], w1 = wL[ib + k * 3 + 1], w2 = wL[ib + k * 3 + 2];
        a0 += w0 * bf2f(Y[((size_t)i0 * 25 + k) * COUTP + ch]);
        a1 += w1 * bf2f(Y[((size_t)i1 * 25 + k) * COUTP + ch]);
        a2 += w2 * bf2f(Y[((size_t)i2 * 25 + k) * COUTP + ch]);
    }
    if (ch < COUT) {
        float v = a0 + a1 + a2 + bias[ch];
        if constexpr (FINAL) {
            if (*flag) ((float*)Ob)[(size_t)n * COUT + ch] = v;
            else       ((unsigned short*)Ob)[(size_t)n * COUT + ch] = f2bf(v);
        } else {
            pre[(size_t)n * COUT + ch] = v;
        }
    }
}

template<int C>
__global__ __launch_bounds__(256) void stats_k(const float* __restrict__ pre,
                                               float* __restrict__ part)
{
    constexpr int RG = 256 / C;
    constexpr int CH = (NN + 63) / 64;
    const int b = blockIdx.x;
    const int r0 = b * CH;
    const int r1 = imin(NN, r0 + CH);
    const int c = threadIdx.x % C;
    const int g = threadIdx.x / C;
    float s = 0.f, s2 = 0.f;
    for (int r = r0 + g; r < r1; r += RG) {
        float v = pre[(size_t)r * C + c];
        s += v; s2 += v * v;
    }
    __shared__ float ls[256], ls2[256];
    ls[threadIdx.x] = s; ls2[threadIdx.x] = s2;
    __syncthreads();
    if (threadIdx.x < C) {
        float a = 0.f, a2 = 0.f;
        #pragma unroll
        for (int g2 = 0; g2 < RG; g2++) {
            a  += ls[g2 * C + threadIdx.x];
            a2 += ls2[g2 * C + threadIdx.x];
        }
        part[b * 2 * C + threadIdx.x] = a;
        part[b * 2 * C + C + threadIdx.x] = a2;
    }
}

template<int C>
__global__ __launch_bounds__(256) void bn_k(const float* __restrict__ pre,
                                            const float* __restrict__ part,
                                            const float* __restrict__ gm,
                                            const float* __restrict__ bt,
                                            unsigned short* __restrict__ act)
{
    __shared__ float sc[C], sh[C];
    if (threadIdx.x < C) {
        const int c = threadIdx.x;
        float s = 0.f, s2 = 0.f;
        for (int b = 0; b < 64; b++) {
            s  += part[b * 2 * C + c];
            s2 += part[b * 2 * C + C + c];
        }
        const float inv = 1.f / (float)NN;
        float mu = s * inv;
        float var = s2 * inv - mu * mu;
        float scale = gm[c] * rsqrtf(var + 1e-5f);
        sc[c] = scale;
        sh[c] = bt[c] - mu * scale;
    }
    __syncthreads();
    const int chunk = (NN + gridDim.x - 1) / gridDim.x;
    const int r0 = blockIdx.x * chunk;
    const int r1 = imin(NN, r0 + chunk);
    for (int i = r0 * C + threadIdx.x; i < r1 * C; i += 256) {
        const int c = i % C;
        float v = fmaxf(pre[i] * sc[c] + sh[c], 0.f);
        act[i] = f2bf(v);
    }
}

extern "C" void kernel_launch(void* const* d_in, const int* in_sizes, int n_in,
                              void* d_out, int out_size, void* d_ws, size_t ws_size,
                              hipStream_t stream) {
    const void* x    = d_in[0];
    const int*  idx  = (const int*)d_in[1];
    const void* wgt  = d_in[2];
    const void* W1   = d_in[3];
    const void* b1   = d_in[4];
    const void* g1   = d_in[5];
    const void* be1  = d_in[6];
    const void* W2   = d_in[7];
    const void* b2   = d_in[8];
    const void* g2   = d_in[9];
    const void* be2  = d_in[10];
    const void* W3   = d_in[11];
    const void* b3   = d_in[12];
    const void* g3   = d_in[13];
    const void* be3  = d_in[14];
    const void* Wout = d_in[15];
    const void* bout = d_in[16];

    char* ws = (char*)d_ws;
    size_t off = 0;
    auto alloc = [&](size_t bytes) {
        off = (off + 255) & ~(size_t)255;
        size_t o = off; off += bytes; return o;
    };
    const size_t o_flag = alloc(4);
    const size_t o_xc   = alloc((size_t)NN * 3 * 2);
    const size_t o_wgtc = alloc((size_t)NN * 75 * 4);
    const size_t o_W1c  = alloc(64 * 80 * 2);
    const size_t o_Bt2  = alloc((size_t)8 * 1792 * 8 * 2);
    const size_t o_Bt3  = alloc((size_t)8 * 3328 * 8 * 2);
    const size_t o_Bt4  = alloc((size_t)16 * 1280 * 8 * 2);
    const size_t o_bias = alloc(1024 * 4);
    const size_t o_pre  = alloc((size_t)NN * 128 * 4);
    const size_t o_actA = alloc((size_t)NN * 128 * 2);
    const size_t o_actB = alloc((size_t)NN * 64 * 2);
    const size_t o_part = alloc((size_t)64 * 2 * 128 * 4);
    const size_t o_Y    = alloc((size_t)NN * 3200 * 2);
    if (ws_size < off) return;

    int* flag = (int*)(ws + o_flag);
    unsigned short* xc  = (unsigned short*)(ws + o_xc);
    float* wgtc = (float*)(ws + o_wgtc);
    unsigned short* W1c = (unsigned short*)(ws + o_W1c);
    unsigned short* Bt2 = (unsigned short*)(ws + o_Bt2);
    unsigned short* Bt3 = (unsigned short*)(ws + o_Bt3);
    unsigned short* Bt4 = (unsigned short*)(ws + o_Bt4);
    float* biasc = (float*)(ws + o_bias);
    float* pre  = (float*)(ws + o_pre);
    unsigned short* actA = (unsigned short*)(ws + o_actA);
    unsigned short* actB = (unsigned short*)(ws + o_actB);
    float* part = (float*)(ws + o_part);
    unsigned short* Y = (unsigned short*)(ws + o_Y);

    detect_k<<<1, 64, 0, stream>>>(wgt, flag);

    Tab t;
    t.s[0]  = { x,    xc,   NN * 3,        NN * 3,  0, 0, 0, 0, 0 };
    t.s[1]  = { wgt,  wgtc, NN * 75,       NN * 75, 1, 0, 0, 0, 0 };
    t.s[2]  = { W1,   W1c,  64 * 80,       64 * 80, 2, 0, 0, 0, 0 };
    t.s[3]  = { W2,   Bt2,  8 * 1792 * 8,  0, 4, 1600, 64,  1792, 64 };
    t.s[4]  = { W3,   Bt3,  8 * 3328 * 8,  0, 4, 1600, 128, 3328, 128 };
    t.s[5]  = { Wout, Bt4,  16 * 1280 * 8, 0, 4, 3200, 36,  1280, 48 };
    t.s[6]  = { b1,   biasc + 0,   64, 64, 1, 0, 0, 0, 0 };
    t.s[7]  = { g1,   biasc + 64,  64, 64, 1, 0, 0, 0, 0 };
    t.s[8]  = { be1,  biasc + 128, 64, 64, 1, 0, 0, 0, 0 };
    t.s[9]  = { b2,   biasc + 192, 64, 64, 1, 0, 0, 0, 0 };
    t.s[10] = { g2,   biasc + 256, 64, 64, 1, 0, 0, 0, 0 };
    t.s[11] = { be2,  biasc + 320, 64, 64, 1, 0, 0, 0, 0 };
    t.s[12] = { b3,   biasc + 384, 128, 128, 1, 0, 0, 0, 0 };
    t.s[13] = { g3,   biasc + 512, 128, 128, 1, 0, 0, 0, 0 };
    t.s[14] = { be3,  biasc + 640, 128, 128, 1, 0, 0, 0, 0 };
    t.s[15] = { bout, biasc + 768, 36, 36, 1, 0, 0, 0, 0 };
    canon_k<<<dim3(768, 16), 256, 0, stream>>>(t, flag);

    dim3 B(256);
    // layer 1: 3 -> 64 (VALU, K=80)
    conv_k<3, 64, 64, 16><<<641, B, 0, stream>>>(xc, idx, wgtc, W1c, biasc + 0, pre);
    stats_k<64><<<64, B, 0, stream>>>(pre, part);
    bn_k<64><<<128, B, 0, stream>>>(pre, part, biasc + 64, biasc + 128, actA);
    // layer 2: 64 -> 64 : dense GEMM to Y-space, then streaming combine
    gemmy_k<64, 1600, 1792><<<dim3(161, 7), B, 0, stream>>>(actA, Bt2, Y);
    comb_k<64, 64, 1, false><<<2561, B, 0, stream>>>(Y, idx, wgtc, biasc + 192, pre, nullptr, flag);
    stats_k<64><<<64, B, 0, stream>>>(pre, part);
    bn_k<64><<<128, B, 0, stream>>>(pre, part, biasc + 256, biasc + 320, actB);
    // layer 3: 64 -> 128
    gemmy_k<64, 3200, 3328><<<dim3(161, 13), B, 0, stream>>>(actB, Bt3, Y);
    comb_k<128, 128, 2, false><<<5121, B, 0, stream>>>(Y, idx, wgtc, biasc + 384, pre, nullptr, flag);
    stats_k<128><<<64, B, 0, stream>>>(pre, part);
    bn_k<128><<<128, B, 0, stream>>>(pre, part, biasc + 512, biasc + 640, actA);
    // layer 4: 128 -> 36 (COUTP=48 padded)
    gemmy_k<128, 1200, 1280><<<dim3(161, 5), B, 0, stream>>>(actA, Bt4, Y);
    comb_k<48, 36, 1, true><<<2561, B, 0, stream>>>(Y, idx, wgtc, biasc + 768, nullptr, d_out, flag);
}

// Round 12
// 194.719 us; speedup vs baseline: 1.4818x; 1.4818x over previous
//
#include <hip/hip_runtime.h>

#define NN 10242

typedef short s8v __attribute__((ext_vector_type(8)));
typedef unsigned int u32x4 __attribute__((ext_vector_type(4)));
typedef float f32x4 __attribute__((ext_vector_type(4)));

static __device__ __forceinline__ float bf2f(unsigned short u) {
    unsigned int i = ((unsigned int)u) << 16;
    return __builtin_bit_cast(float, i);
}
static __device__ __forceinline__ unsigned short f2bf(float f) {
    unsigned int i = __builtin_bit_cast(unsigned int, f);
    unsigned int lsb = (i >> 16) & 1u;
    i += 0x7fffu + lsb;
    return (unsigned short)(i >> 16);
}
static __device__ __forceinline__ unsigned int cvtpk(float lo, float hi) {
    unsigned int r;
    asm("v_cvt_pk_bf16_f32 %0, %1, %2" : "=v"(r) : "v"(lo), "v"(hi));
    return r;
}
static __device__ __forceinline__ void gl_lds16(const unsigned short* g, unsigned short* l) {
    __builtin_amdgcn_global_load_lds(
        (const __attribute__((address_space(1))) unsigned int*)g,
        (__attribute__((address_space(3))) unsigned int*)l, 16, 0, 0);
}
template<int N> static __device__ __forceinline__ void waitv() {
    asm volatile("s_waitcnt vmcnt(%0)" :: "n"(N) : "memory");
    __builtin_amdgcn_sched_barrier(0);
}
static __device__ __forceinline__ int imin(int a, int b) { return a < b ? a : b; }

// ---- dtype detector ----
__global__ void detect_k(const void* __restrict__ wgt, int* __restrict__ flag) {
    const float* wf = (const float*)wgt;
    const int r = threadIdx.x;
    float s = wf[3 * r] + wf[3 * r + 1] + wf[3 * r + 2];
    bool ok = (s == s) && (fabsf(s - 1.f) < 0.05f);
    unsigned long long m = __ballot(ok);
    if (r == 0) *flag = (__popcll(m) >= 60) ? 1 : 0;
}

// ---- canonicalizer ----
// mode 0: ->bf16  mode 1: ->f32  mode 2: W1 75->80 ->bf16
// mode 3: W[cout][K] -> Wt[K/8][cpad][8] bf16 (zero rows cout..cpad-1)
struct Seg { const void* src; void* dst; int n; int nsrc; int mode; int K; int cout; int cpad; };
struct Tab { Seg s[16]; };

__global__ __launch_bounds__(256) void canon_k(Tab t, const int* __restrict__ flag) {
    const Seg sg = t.s[blockIdx.y];
    const bool f32src = (*flag != 0);
    for (int i = blockIdx.x * 256 + threadIdx.x; i < sg.n; i += gridDim.x * 256) {
        if (sg.mode == 0) {
            unsigned short v = 0;
            if (i < sg.nsrc)
                v = f32src ? f2bf(((const float*)sg.src)[i])
                           : ((const unsigned short*)sg.src)[i];
            ((unsigned short*)sg.dst)[i] = v;
        } else if (sg.mode == 1) {
            float v = f32src ? ((const float*)sg.src)[i]
                             : bf2f(((const unsigned short*)sg.src)[i]);
            ((float*)sg.dst)[i] = v;
        } else if (sg.mode == 2) {
            const int row = i / 80, col = i - row * 80;
            unsigned short v = 0;
            if (col < 75) {
                const int j = row * 75 + col;
                v = f32src ? f2bf(((const float*)sg.src)[j])
                           : ((const unsigned short*)sg.src)[j];
            }
            ((unsigned short*)sg.dst)[i] = v;
        } else {
            const int e = i & 7;
            const int r = i >> 3;
            const int c = r % sg.cpad;
            const int k8 = r / sg.cpad;
            unsigned short v = 0;
            if (c < sg.cout) {
                const int j = c * sg.K + k8 * 8 + e;
                v = f32src ? f2bf(((const float*)sg.src)[j])
                           : ((const unsigned short*)sg.src)[j];
            }
            ((unsigned short*)sg.dst)[i] = v;
        }
    }
}

// ---- layer-1 conv (K=80, VALU; proven) ----
template<int CIN, int COUT, int CG, int NB>
__global__ __launch_bounds__(256) void conv_k(
    const unsigned short* __restrict__ X,
    const int* __restrict__ idx,
    const float* __restrict__ wgt,
    const unsigned short* __restrict__ W,
    const float* __restrict__ bias,
    float* __restrict__ Of)
{
    constexpr int K = 25 * CIN;
    constexpr int KPAD = (K + 7) & ~7;
    __shared__ unsigned short agg[NB][KPAD];
    const int tid = threadIdx.x;
    const int n0 = blockIdx.x * NB;

    for (int p = tid; p < NB * 25; p += 256) {
        const int r = p / 25;
        const int k = p - r * 25;
        const int n = n0 + r;
        if (n < NN) {
            const int base = n * 75 + k * 3;
            const int i0 = idx[base], i1 = idx[base + 1], i2 = idx[base + 2];
            const float w0 = wgt[base], w1 = wgt[base + 1], w2 = wgt[base + 2];
            for (int e = 0; e < CIN; e++) {
                float v = w0 * bf2f(X[i0 * CIN + e]) +
                          w1 * bf2f(X[i1 * CIN + e]) +
                          w2 * bf2f(X[i2 * CIN + e]);
                agg[r][k * CIN + e] = f2bf(v);
            }
        } else {
            for (int e = 0; e < CIN; e++) agg[r][k * CIN + e] = 0;
        }
    }
    if constexpr (KPAD != K) {
        for (int p = tid; p < NB * (KPAD - K); p += 256) {
            const int r = p / (KPAD - K);
            agg[r][K + p - r * (KPAD - K)] = 0;
        }
    }
    __syncthreads();

    constexpr int RG = 256 / CG;
    constexpr int RPT = NB / RG;
    const int c = tid % CG;
    const int rq = tid / CG;
    float acc[RPT] = {};
    if (c < COUT) {
        const unsigned short* Wr = W + (size_t)c * KPAD;
        for (int j = 0; j < KPAD; j += 8) {
            s8v wv = *(const s8v*)(Wr + j);
            float wf[8];
            #pragma unroll
            for (int q = 0; q < 8; q++) wf[q] = bf2f((unsigned short)wv[q]);
            #pragma unroll
            for (int rr = 0; rr < RPT; rr++) {
                s8v av = *(const s8v*)(&agg[rq * RPT + rr][j]);
                #pragma unroll
                for (int q = 0; q < 8; q++)
                    acc[rr] += wf[q] * bf2f((unsigned short)av[q]);
            }
        }
        const float bb = bias[c];
        #pragma unroll
        for (int rr = 0; rr < RPT; rr++) {
            const int n = n0 + rq * RPT + rr;
            if (n < NN) Of[(size_t)n * COUT + c] = acc[rr] + bb;
        }
    }
}

// ---- DMA-pipelined gather conv ----
// Block = 16 nodes, 4 waves. Rows (node,vert[+pad]) = 64/slot; global_load_lds
// gathers them into a 4-deep LDS ring; counted vmcnt + 2 raw barriers/slot.
// Lane (l15=node, kg): interp a-frag in regs, MFMA vs Wt[K/8][COUTP][8].
template<int CIN, int COUTP, int COUT, bool FINAL>
__global__ __launch_bounds__(256, 2) void convdma_k(
    const unsigned short* __restrict__ X,
    const int* __restrict__ idx,
    const float* __restrict__ wgt,
    const unsigned short* __restrict__ Wt,
    const float* __restrict__ bias,
    float* __restrict__ pre,
    void* __restrict__ Ob,
    const int* __restrict__ flag)
{
    constexpr int NT = CIN / 32;             // K-steps per slot
    constexpr int NFRAG = COUTP / 64;        // 16-col frags per wave
    constexpr int INSTS = CIN / 8;           // 1024B DMA insts per slot (8/16)
    constexpr int Q = INSTS / 4;             // insts per wave per slot
    constexpr int R = NT * NFRAG;            // B-frag loads per wave per slot
    __shared__ unsigned short raw[4 * 64 * CIN];
    __shared__ int   iL[25 * 64];
    __shared__ float wL[25 * 48];
    const int tid = threadIdx.x;
    const int n0 = blockIdx.x * 16;

    // stage idx/wgt (rows padded: vert 3 -> idx 0)
    for (int q = tid; q < 16 * 75; q += 256) {
        const int node = q / 75, f = q - node * 75;
        const int k = f / 3, v = f - k * 3;
        const int n = n0 + node;
        const bool ok = n < NN;
        const int g = ok ? (n * 75 + f) : 0;
        iL[k * 64 + node * 4 + v] = ok ? idx[g] : 0;
        wL[k * 48 + node * 3 + v] = ok ? wgt[g] : 0.f;
    }
    for (int q = tid; q < 25 * 16; q += 256)
        iL[(q / 16) * 64 + (q - (q / 16) * 16) * 4 + 3] = 0;
    __syncthreads();

    const int wv = tid >> 6;
    const int lane = tid & 63;
    const int l15 = lane & 15;
    const int kg = lane >> 4;
    const int colbase = wv * NFRAG * 16;

    // DMA issue: wave's Q insts for slot sd; source chunk XOR-swizzled by node
    auto issue = [&](int sd) {
        const int base = (sd & 3) * (64 * CIN);
        #pragma unroll
        for (int jj = 0; jj < Q; jj++) {
            const int j = wv * Q + jj;
            int row, p;
            if constexpr (CIN == 64) { row = j * 8 + (lane >> 3); p = lane & 7; }
            else                     { row = j * 4 + (lane >> 4); p = lane & 15; }
            const int ch = p ^ ((row >> 2) & 7);
            const int id = iL[sd * 64 + row];
            gl_lds16(X + (size_t)id * CIN + ch * 8, &raw[base + j * 512]);
        }
    };
    auto loadB = [&](int sp, s8v* dst) {
        #pragma unroll
        for (int t = 0; t < NT; t++)
            #pragma unroll
            for (int j = 0; j < NFRAG; j++)
                dst[t * NFRAG + j] = *(const s8v*)(Wt +
                    ((size_t)(sp * (CIN / 8) + t * 4 + kg) * COUTP + colbase + j * 16 + l15) * 8);
    };

    f32x4 acc[NFRAG] = {};
    s8v breg[2][R];

    // prologue: DMA0, B0, DMA1, DMA2
    issue(0);
    loadB(0, breg[0]);
    issue(1);
    issue(2);

    #pragma unroll
    for (int s = 0; s < 25; s++) {
        __builtin_amdgcn_s_barrier();        // all finished compute s-1
        if (s + 1 < 25) loadB(s + 1, breg[(s + 1) & 1]);
        if (s + 3 < 25) issue(s + 3);
        if (s == 0)       waitv<3 * Q + R>();
        else if (s < 22)  waitv<2 * Q + R>();
        else if (s == 22) waitv<Q + R>();
        else if (s == 23) waitv<R>();
        else              waitv<0>();
        __builtin_amdgcn_s_barrier();        // everyone's slot-s DMA landed
        const int rb = (s & 3) * (64 * CIN) + l15 * 4 * CIN;
        const float w0 = wL[s * 48 + l15 * 3 + 0];
        const float w1 = wL[s * 48 + l15 * 3 + 1];
        const float w2 = wL[s * 48 + l15 * 3 + 2];
        #pragma unroll
        for (int t = 0; t < NT; t++) {
            const int p = (t * 4 + kg) ^ (l15 & 7);
            const s8v va = *(const s8v*)(&raw[rb + 0 * CIN + p * 8]);
            const s8v vb = *(const s8v*)(&raw[rb + 1 * CIN + p * 8]);
            const s8v vc = *(const s8v*)(&raw[rb + 2 * CIN + p * 8]);
            u32x4 au;
            #pragma unroll
            for (int qq = 0; qq < 4; qq++) {
                const float lo = w0 * bf2f((unsigned short)va[2 * qq]) +
                                 w1 * bf2f((unsigned short)vb[2 * qq]) +
                                 w2 * bf2f((unsigned short)vc[2 * qq]);
                const float hi = w0 * bf2f((unsigned short)va[2 * qq + 1]) +
                                 w1 * bf2f((unsigned short)vb[2 * qq + 1]) +
                                 w2 * bf2f((unsigned short)vc[2 * qq + 1]);
                au[qq] = cvtpk(lo, hi);
            }
            const s8v a = __builtin_bit_cast(s8v, au);
            #pragma unroll
            for (int j = 0; j < NFRAG; j++)
                acc[j] = __builtin_amdgcn_mfma_f32_16x16x32_bf16(a, breg[s & 1][t * NFRAG + j], acc[j], 0, 0, 0);
        }
    }

    bool f32o = false;
    if constexpr (FINAL) f32o = (*flag != 0);
    #pragma unroll
    for (int j = 0; j < NFRAG; j++) {
        const int col = colbase + j * 16 + l15;
        if (col < COUT) {
            const float bb = bias[col];
            #pragma unroll
            for (int q = 0; q < 4; q++) {
                const int n = n0 + kg * 4 + q;       // C row = (lane>>4)*4 + reg
                if (n < NN) {
                    const float v = acc[j][q] + bb;
                    if constexpr (FINAL) {
                        if (f32o) ((float*)Ob)[(size_t)n * COUT + col] = v;
                        else ((unsigned short*)Ob)[(size_t)n * COUT + col] = f2bf(v);
                    } else {
                        pre[(size_t)n * COUT + col] = v;
                    }
                }
            }
        }
    }
}

template<int C>
__global__ __launch_bounds__(256) void stats_k(const float* __restrict__ pre,
                                               float* __restrict__ part)
{
    constexpr int RG = 256 / C;
    constexpr int CH = (NN + 63) / 64;
    const int b = blockIdx.x;
    const int r0 = b * CH;
    const int r1 = imin(NN, r0 + CH);
    const int c = threadIdx.x % C;
    const int g = threadIdx.x / C;
    float s = 0.f, s2 = 0.f;
    for (int r = r0 + g; r < r1; r += RG) {
        float v = pre[(size_t)r * C + c];
        s += v; s2 += v * v;
    }
    __shared__ float ls[256], ls2[256];
    ls[threadIdx.x] = s; ls2[threadIdx.x] = s2;
    __syncthreads();
    if (threadIdx.x < C) {
        float a = 0.f, a2 = 0.f;
        #pragma unroll
        for (int g2 = 0; g2 < RG; g2++) {
            a  += ls[g2 * C + threadIdx.x];
            a2 += ls2[g2 * C + threadIdx.x];
        }
        part[b * 2 * C + threadIdx.x] = a;
        part[b * 2 * C + C + threadIdx.x] = a2;
    }
}

template<int C>
__global__ __launch_bounds__(256) void bn_k(const float* __restrict__ pre,
                                            const float* __restrict__ part,
                                            const float* __restrict__ gm,
                                            const float* __restrict__ bt,
                                            unsigned short* __restrict__ act)
{
    __shared__ float sc[C], sh[C];
    if (threadIdx.x < C) {
        const int c = threadIdx.x;
        float s = 0.f, s2 = 0.f;
        for (int b = 0; b < 64; b++) {
            s  += part[b * 2 * C + c];
            s2 += part[b * 2 * C + C + c];
        }
        const float inv = 1.f / (float)NN;
        float mu = s * inv;
        float var = s2 * inv - mu * mu;
        float scale = gm[c] * rsqrtf(var + 1e-5f);
        sc[c] = scale;
        sh[c] = bt[c] - mu * scale;
    }
    __syncthreads();
    const int chunk = (NN + gridDim.x - 1) / gridDim.x;
    const int r0 = blockIdx.x * chunk;
    const int r1 = imin(NN, r0 + chunk);
    for (int i = r0 * C + threadIdx.x; i < r1 * C; i += 256) {
        const int c = i % C;
        float v = fmaxf(pre[i] * sc[c] + sh[c], 0.f);
        act[i] = f2bf(v);
    }
}

extern "C" void kernel_launch(void* const* d_in, const int* in_sizes, int n_in,
                              void* d_out, int out_size, void* d_ws, size_t ws_size,
                              hipStream_t stream) {
    const void* x    = d_in[0];
    const int*  idx  = (const int*)d_in[1];
    const void* wgt  = d_in[2];
    const void* W1   = d_in[3];
    const void* b1   = d_in[4];
    const void* g1   = d_in[5];
    const void* be1  = d_in[6];
    const void* W2   = d_in[7];
    const void* b2   = d_in[8];
    const void* g2   = d_in[9];
    const void* be2  = d_in[10];
    const void* W3   = d_in[11];
    const void* b3   = d_in[12];
    const void* g3   = d_in[13];
    const void* be3  = d_in[14];
    const void* Wout = d_in[15];
    const void* bout = d_in[16];

    char* ws = (char*)d_ws;
    size_t off = 0;
    auto alloc = [&](size_t bytes) {
        off = (off + 255) & ~(size_t)255;
        size_t o = off; off += bytes; return o;
    };
    const size_t o_flag = alloc(4);
    const size_t o_xc   = alloc((size_t)NN * 3 * 2);
    const size_t o_wgtc = alloc((size_t)NN * 75 * 4);
    const size_t o_W1c  = alloc(64 * 80 * 2);
    const size_t o_Wt2  = alloc((size_t)200 * 64 * 8 * 2);
    const size_t o_Wt3  = alloc((size_t)200 * 128 * 8 * 2);
    const size_t o_Wt4  = alloc((size_t)400 * 64 * 8 * 2);
    const size_t o_bias = alloc(1024 * 4);
    const size_t o_pre  = alloc((size_t)NN * 128 * 4);
    const size_t o_actA = alloc((size_t)NN * 128 * 2);
    const size_t o_actB = alloc((size_t)NN * 64 * 2);
    const size_t o_part = alloc((size_t)64 * 2 * 128 * 4);
    if (ws_size < off) return;

    int* flag = (int*)(ws + o_flag);
    unsigned short* xc  = (unsigned short*)(ws + o_xc);
    float* wgtc = (float*)(ws + o_wgtc);
    unsigned short* W1c = (unsigned short*)(ws + o_W1c);
    unsigned short* Wt2 = (unsigned short*)(ws + o_Wt2);
    unsigned short* Wt3 = (unsigned short*)(ws + o_Wt3);
    unsigned short* Wt4 = (unsigned short*)(ws + o_Wt4);
    float* biasc = (float*)(ws + o_bias);
    float* pre  = (float*)(ws + o_pre);
    unsigned short* actA = (unsigned short*)(ws + o_actA);
    unsigned short* actB = (unsigned short*)(ws + o_actB);
    float* part = (float*)(ws + o_part);

    detect_k<<<1, 64, 0, stream>>>(wgt, flag);

    Tab t;
    t.s[0]  = { x,    xc,   NN * 3,         NN * 3,  0, 0, 0, 0 };
    t.s[1]  = { wgt,  wgtc, NN * 75,        NN * 75, 1, 0, 0, 0 };
    t.s[2]  = { W1,   W1c,  64 * 80,        64 * 80, 2, 0, 0, 0 };
    t.s[3]  = { W2,   Wt2,  200 * 64 * 8,   0,       3, 1600, 64, 64 };
    t.s[4]  = { W3,   Wt3,  200 * 128 * 8,  0,       3, 1600, 128, 128 };
    t.s[5]  = { Wout, Wt4,  400 * 64 * 8,   0,       3, 3200, 36, 64 };
    t.s[6]  = { b1,   biasc + 0,   64, 64, 1, 0, 0, 0 };
    t.s[7]  = { g1,   biasc + 64,  64, 64, 1, 0, 0, 0 };
    t.s[8]  = { be1,  biasc + 128, 64, 64, 1, 0, 0, 0 };
    t.s[9]  = { b2,   biasc + 192, 64, 64, 1, 0, 0, 0 };
    t.s[10] = { g2,   biasc + 256, 64, 64, 1, 0, 0, 0 };
    t.s[11] = { be2,  biasc + 320, 64, 64, 1, 0, 0, 0 };
    t.s[12] = { b3,   biasc + 384, 128, 128, 1, 0, 0, 0 };
    t.s[13] = { g3,   biasc + 512, 128, 128, 1, 0, 0, 0 };
    t.s[14] = { be3,  biasc + 640, 128, 128, 1, 0, 0, 0 };
    t.s[15] = { bout, biasc + 768, 36, 36, 1, 0, 0, 0 };
    canon_k<<<dim3(768, 16), 256, 0, stream>>>(t, flag);

    dim3 B(256);
    // layer 1: 3 -> 64 (VALU, K=80)
    conv_k<3, 64, 64, 16><<<641, B, 0, stream>>>(xc, idx, wgtc, W1c, biasc + 0, pre);
    stats_k<64><<<64, B, 0, stream>>>(pre, part);
    bn_k<64><<<128, B, 0, stream>>>(pre, part, biasc + 64, biasc + 128, actA);
    // layer 2: 64 -> 64 (DMA-pipelined)
    convdma_k<64, 64, 64, false><<<641, B, 0, stream>>>(
        actA, idx, wgtc, Wt2, biasc + 192, pre, nullptr, flag);
    stats_k<64><<<64, B, 0, stream>>>(pre, part);
    bn_k<64><<<128, B, 0, stream>>>(pre, part, biasc + 256, biasc + 320, actB);
    // layer 3: 64 -> 128
    convdma_k<64, 128, 128, false><<<641, B, 0, stream>>>(
        actB, idx, wgtc, Wt3, biasc + 384, pre, nullptr, flag);
    stats_k<128><<<64, B, 0, stream>>>(pre, part);
    bn_k<128><<<128, B, 0, stream>>>(pre, part, biasc + 512, biasc + 640, actA);
    // layer 4: 128 -> 36 (COUTP=64 padded), direct to d_out
    convdma_k<128, 64, 36, true><<<641, B, 0, stream>>>(
        actA, idx, wgtc, Wt4, biasc + 768, nullptr, d_out, flag);
}

// Round 13
// 162.503 us; speedup vs baseline: 1.7756x; 1.1983x over previous
//
#include <hip/hip_runtime.h>

#define NN 10242

typedef short s8v __attribute__((ext_vector_type(8)));
typedef unsigned int u32x2 __attribute__((ext_vector_type(2)));
typedef float f32x4 __attribute__((ext_vector_type(4)));

static __device__ __forceinline__ float bf2f(unsigned short u) {
    unsigned int i = ((unsigned int)u) << 16;
    return __builtin_bit_cast(float, i);
}
static __device__ __forceinline__ float bfu32lo(unsigned int d) {
    return __builtin_bit_cast(float, d << 16);
}
static __device__ __forceinline__ float bfu32hi(unsigned int d) {
    return __builtin_bit_cast(float, d & 0xffff0000u);
}
static __device__ __forceinline__ unsigned short f2bf(float f) {
    unsigned int i = __builtin_bit_cast(unsigned int, f);
    unsigned int lsb = (i >> 16) & 1u;
    i += 0x7fffu + lsb;
    return (unsigned short)(i >> 16);
}
static __device__ __forceinline__ unsigned int cvtpk(float lo, float hi) {
    unsigned int r;
    asm("v_cvt_pk_bf16_f32 %0, %1, %2" : "=v"(r) : "v"(lo), "v"(hi));
    return r;
}
static __device__ __forceinline__ void gl_lds16(const unsigned short* g, unsigned short* l) {
    __builtin_amdgcn_global_load_lds(
        (const __attribute__((address_space(1))) unsigned int*)g,
        (__attribute__((address_space(3))) unsigned int*)l, 16, 0, 0);
}
template<int N> static __device__ __forceinline__ void waitv() {
    asm volatile("s_waitcnt vmcnt(%0)" :: "n"(N) : "memory");
    __builtin_amdgcn_sched_barrier(0);
}
static __device__ __forceinline__ void lgkm0() {
    asm volatile("s_waitcnt lgkmcnt(0)" ::: "memory");
    __builtin_amdgcn_sched_barrier(0);
}
static __device__ __forceinline__ int imin(int a, int b) { return a < b ? a : b; }

// ---- dtype detector ----
__global__ void detect_k(const void* __restrict__ wgt, int* __restrict__ flag) {
    const float* wf = (const float*)wgt;
    const int r = threadIdx.x;
    float s = wf[3 * r] + wf[3 * r + 1] + wf[3 * r + 2];
    bool ok = (s == s) && (fabsf(s - 1.f) < 0.05f);
    unsigned long long m = __ballot(ok);
    if (r == 0) *flag = (__popcll(m) >= 60) ? 1 : 0;
}

// ---- canonicalizer ----
// mode 0: ->bf16  mode 1: ->f32  mode 2: W1 75->80 ->bf16
// mode 3: W[cout][K] -> Wt[K/8][cpad][8] bf16 (zero rows cout..cpad-1)
struct Seg { const void* src; void* dst; int n; int nsrc; int mode; int K; int cout; int cpad; };
struct Tab { Seg s[16]; };

__global__ __launch_bounds__(256) void canon_k(Tab t, const int* __restrict__ flag) {
    const Seg sg = t.s[blockIdx.y];
    const bool f32src = (*flag != 0);
    for (int i = blockIdx.x * 256 + threadIdx.x; i < sg.n; i += gridDim.x * 256) {
        if (sg.mode == 0) {
            unsigned short v = 0;
            if (i < sg.nsrc)
                v = f32src ? f2bf(((const float*)sg.src)[i])
                           : ((const unsigned short*)sg.src)[i];
            ((unsigned short*)sg.dst)[i] = v;
        } else if (sg.mode == 1) {
            float v = f32src ? ((const float*)sg.src)[i]
                             : bf2f(((const unsigned short*)sg.src)[i]);
            ((float*)sg.dst)[i] = v;
        } else if (sg.mode == 2) {
            const int row = i / 80, col = i - row * 80;
            unsigned short v = 0;
            if (col < 75) {
                const int j = row * 75 + col;
                v = f32src ? f2bf(((const float*)sg.src)[j])
                           : ((const unsigned short*)sg.src)[j];
            }
            ((unsigned short*)sg.dst)[i] = v;
        } else {
            const int e = i & 7;
            const int r = i >> 3;
            const int c = r % sg.cpad;
            const int k8 = r / sg.cpad;
            unsigned short v = 0;
            if (c < sg.cout) {
                const int j = c * sg.K + k8 * 8 + e;
                v = f32src ? f2bf(((const float*)sg.src)[j])
                           : ((const unsigned short*)sg.src)[j];
            }
            ((unsigned short*)sg.dst)[i] = v;
        }
    }
}

// ---- layer-1 conv (K=80, VALU; proven) ----
template<int CIN, int COUT, int CG, int NB>
__global__ __launch_bounds__(256) void conv_k(
    const unsigned short* __restrict__ X,
    const int* __restrict__ idx,
    const float* __restrict__ wgt,
    const unsigned short* __restrict__ W,
    const float* __restrict__ bias,
    float* __restrict__ Of)
{
    constexpr int K = 25 * CIN;
    constexpr int KPAD = (K + 7) & ~7;
    __shared__ unsigned short agg[NB][KPAD];
    const int tid = threadIdx.x;
    const int n0 = blockIdx.x * NB;

    for (int p = tid; p < NB * 25; p += 256) {
        const int r = p / 25;
        const int k = p - r * 25;
        const int n = n0 + r;
        if (n < NN) {
            const int base = n * 75 + k * 3;
            const int i0 = idx[base], i1 = idx[base + 1], i2 = idx[base + 2];
            const float w0 = wgt[base], w1 = wgt[base + 1], w2 = wgt[base + 2];
            for (int e = 0; e < CIN; e++) {
                float v = w0 * bf2f(X[i0 * CIN + e]) +
                          w1 * bf2f(X[i1 * CIN + e]) +
                          w2 * bf2f(X[i2 * CIN + e]);
                agg[r][k * CIN + e] = f2bf(v);
            }
        } else {
            for (int e = 0; e < CIN; e++) agg[r][k * CIN + e] = 0;
        }
    }
    if constexpr (KPAD != K) {
        for (int p = tid; p < NB * (KPAD - K); p += 256) {
            const int r = p / (KPAD - K);
            agg[r][K + p - r * (KPAD - K)] = 0;
        }
    }
    __syncthreads();

    constexpr int RG = 256 / CG;
    constexpr int RPT = NB / RG;
    const int c = tid % CG;
    const int rq = tid / CG;
    float acc[RPT] = {};
    if (c < COUT) {
        const unsigned short* Wr = W + (size_t)c * KPAD;
        for (int j = 0; j < KPAD; j += 8) {
            s8v wv = *(const s8v*)(Wr + j);
            float wf[8];
            #pragma unroll
            for (int q = 0; q < 8; q++) wf[q] = bf2f((unsigned short)wv[q]);
            #pragma unroll
            for (int rr = 0; rr < RPT; rr++) {
                s8v av = *(const s8v*)(&agg[rq * RPT + rr][j]);
                #pragma unroll
                for (int q = 0; q < 8; q++)
                    acc[rr] += wf[q] * bf2f((unsigned short)av[q]);
            }
        }
        const float bb = bias[c];
        #pragma unroll
        for (int rr = 0; rr < RPT; rr++) {
            const int n = n0 + rq * RPT + rr;
            if (n < NN) Of[(size_t)n * COUT + c] = acc[rr] + bb;
        }
    }
}

// ---- DMA-pipelined gather conv v2: DEDUPED interp via agg LDS ring ----
// Block = 16 nodes, 4 waves. Per slot: counted-vmcnt wait on DMA'd raw rows ->
// all 256 threads interp once into agg[2][16][CIN+8] -> each wave MFMAs its
// own COUTP/4-column group from agg. Wave(wv)=col group; lane(l15,kg) std frag.
template<int CIN, int COUTP, int COUT, int RING, bool FINAL>
__global__ __launch_bounds__(256, 3) void convdma2_k(
    const unsigned short* __restrict__ X,
    const int* __restrict__ idx,
    const float* __restrict__ wgt,
    const unsigned short* __restrict__ Wt,   // [K/8][COUTP][8]
    const float* __restrict__ bias,
    float* __restrict__ pre,
    void* __restrict__ Ob,
    const int* __restrict__ flag)
{
    constexpr int NT = CIN / 32;
    constexpr int NFRAG = COUTP / 64;        // cols per wave / 16
    constexpr int INSTS = CIN / 8;           // 1024B DMA insts per slot
    constexpr int Q = INSTS / 4;             // per wave
    constexpr int R = NT * NFRAG;            // B-frag loads per wave per slot
    constexpr int UPNS = (CIN == 64) ? 4 : 5;
    constexpr int UNITS = 16 << UPNS;        // 4-elem interp units per slot
    __shared__ unsigned short raw[RING * 64 * CIN];
    __shared__ unsigned short agg[2][16][CIN + 8];
    __shared__ int   iL[25 * 64];
    __shared__ float wL[25 * 48];
    const int tid = threadIdx.x;
    const int n0 = blockIdx.x * 16;

    // stage idx/wgt (rows per slot: node*4+vert, vert3 = pad -> idx 0)
    for (int q = tid; q < 16 * 75; q += 256) {
        const int node = q / 75, f = q - node * 75;
        const int k = f / 3, v = f - k * 3;
        const int n = n0 + node;
        const bool ok = n < NN;
        const int g = ok ? (n * 75 + f) : 0;
        iL[k * 64 + node * 4 + v] = ok ? idx[g] : 0;
        wL[k * 48 + node * 3 + v] = ok ? wgt[g] : 0.f;
    }
    for (int q = tid; q < 25 * 16; q += 256)
        iL[(q / 16) * 64 + (q - (q / 16) * 16) * 4 + 3] = 0;
    __syncthreads();

    const int wv = tid >> 6;
    const int lane = tid & 63;
    const int l15 = lane & 15;
    const int kg = lane >> 4;
    const int colbase = wv * NFRAG * 16;

    auto issue = [&](int sd) {
        const int base = (sd & (RING - 1)) * (64 * CIN);
        #pragma unroll
        for (int jj = 0; jj < Q; jj++) {
            const int j = wv * Q + jj;
            int row, p;
            if constexpr (CIN == 64) { row = j * 8 + (lane >> 3); p = lane & 7; }
            else                     { row = j * 4 + (lane >> 4); p = lane & 15; }
            const int id = iL[sd * 64 + row];
            gl_lds16(X + (size_t)id * CIN + p * 8, &raw[base + j * 512]);
        }
    };
    auto loadB = [&](int sp, s8v* dst) {
        #pragma unroll
        for (int t = 0; t < NT; t++)
            #pragma unroll
            for (int j = 0; j < NFRAG; j++)
                dst[t * NFRAG + j] = *(const s8v*)(Wt +
                    ((size_t)(sp * (CIN / 8) + t * 4 + kg) * COUTP + colbase + j * 16 + l15) * 8);
    };

    f32x4 acc[NFRAG] = {};
    s8v breg[2][R];

    if constexpr (RING == 4) { issue(0); issue(1); loadB(0, breg[0]); issue(2); }
    else                     { issue(0); loadB(0, breg[0]); issue(1); }

    #pragma unroll
    for (int s = 0; s < 25; s++) {
        if (s + 1 < 25) loadB(s + 1, breg[(s + 1) & 1]);
        if constexpr (RING == 4) {
            if (s <= 22)      waitv<2 * Q + 2 * R>();
            else if (s == 23) waitv<Q + 2 * R>();
            else              waitv<R>();
        } else {
            if (s <= 23)      waitv<Q + 2 * R>();
            else              waitv<R>();
        }
        __builtin_amdgcn_s_barrier();            // raw[s] landed for all
        // ---- cooperative interp: raw[s] -> agg[s&1] (once, all threads) ----
        {
            const int sb = (s & (RING - 1)) * (64 * CIN);
            #pragma unroll
            for (int u = tid; u < UNITS; u += 256) {
                const int node = u >> UPNS;
                const int e4 = u & ((1 << UPNS) - 1);
                const float w0 = wL[s * 48 + node * 3 + 0];
                const float w1 = wL[s * 48 + node * 3 + 1];
                const float w2 = wL[s * 48 + node * 3 + 2];
                const int rb = sb + node * 4 * CIN + e4 * 4;
                const u32x2 A = *(const u32x2*)&raw[rb + 0 * CIN];
                const u32x2 B = *(const u32x2*)&raw[rb + 1 * CIN];
                const u32x2 C = *(const u32x2*)&raw[rb + 2 * CIN];
                const float v0 = w0 * bfu32lo(A[0]) + w1 * bfu32lo(B[0]) + w2 * bfu32lo(C[0]);
                const float v1 = w0 * bfu32hi(A[0]) + w1 * bfu32hi(B[0]) + w2 * bfu32hi(C[0]);
                const float v2 = w0 * bfu32lo(A[1]) + w1 * bfu32lo(B[1]) + w2 * bfu32lo(C[1]);
                const float v3 = w0 * bfu32hi(A[1]) + w1 * bfu32hi(B[1]) + w2 * bfu32hi(C[1]);
                u32x2 o;
                o[0] = cvtpk(v0, v1);
                o[1] = cvtpk(v2, v3);
                *(u32x2*)&agg[s & 1][node][e4 * 4] = o;
            }
        }
        if constexpr (RING == 4) { if (s + 3 < 25) issue(s + 3); }
        lgkm0();
        __builtin_amdgcn_s_barrier();            // agg[s] complete
        if constexpr (RING == 2) {
            if (s + 2 < 25) issue(s + 2);
            __builtin_amdgcn_sched_barrier(0);
        }
        // ---- MFMA over agg[s&1] ----
        #pragma unroll
        for (int t = 0; t < NT; t++) {
            const s8v a = *(const s8v*)(&agg[s & 1][l15][t * 32 + kg * 8]);
            #pragma unroll
            for (int j = 0; j < NFRAG; j++)
                acc[j] = __builtin_amdgcn_mfma_f32_16x16x32_bf16(
                    a, breg[s & 1][t * NFRAG + j], acc[j], 0, 0, 0);
        }
    }

    bool f32o = false;
    if constexpr (FINAL) f32o = (*flag != 0);
    #pragma unroll
    for (int j = 0; j < NFRAG; j++) {
        const int col = colbase + j * 16 + l15;
        if (col < COUT) {
            const float bb = bias[col];
            #pragma unroll
            for (int q = 0; q < 4; q++) {
                const int n = n0 + kg * 4 + q;       // C row = (lane>>4)*4 + reg
                if (n < NN) {
                    const float v = acc[j][q] + bb;
                    if constexpr (FINAL) {
                        if (f32o) ((float*)Ob)[(size_t)n * COUT + col] = v;
                        else ((unsigned short*)Ob)[(size_t)n * COUT + col] = f2bf(v);
                    } else {
                        pre[(size_t)n * COUT + col] = v;
                    }
                }
            }
        }
    }
}

template<int C>
__global__ __launch_bounds__(256) void stats_k(const float* __restrict__ pre,
                                               float* __restrict__ part)
{
    constexpr int RG = 256 / C;
    constexpr int CH = (NN + 63) / 64;
    const int b = blockIdx.x;
    const int r0 = b * CH;
    const int r1 = imin(NN, r0 + CH);
    const int c = threadIdx.x % C;
    const int g = threadIdx.x / C;
    float s = 0.f, s2 = 0.f;
    for (int r = r0 + g; r < r1; r += RG) {
        float v = pre[(size_t)r * C + c];
        s += v; s2 += v * v;
    }
    __shared__ float ls[256], ls2[256];
    ls[threadIdx.x] = s; ls2[threadIdx.x] = s2;
    __syncthreads();
    if (threadIdx.x < C) {
        float a = 0.f, a2 = 0.f;
        #pragma unroll
        for (int g2 = 0; g2 < RG; g2++) {
            a  += ls[g2 * C + threadIdx.x];
            a2 += ls2[g2 * C + threadIdx.x];
        }
        part[b * 2 * C + threadIdx.x] = a;
        part[b * 2 * C + C + threadIdx.x] = a2;
    }
}

template<int C>
__global__ __launch_bounds__(256) void bn_k(const float* __restrict__ pre,
                                            const float* __restrict__ part,
                                            const float* __restrict__ gm,
                                            const float* __restrict__ bt,
                                            unsigned short* __restrict__ act)
{
    __shared__ float sc[C], sh[C];
    if (threadIdx.x < C) {
        const int c = threadIdx.x;
        float s = 0.f, s2 = 0.f;
        for (int b = 0; b < 64; b++) {
            s  += part[b * 2 * C + c];
            s2 += part[b * 2 * C + C + c];
        }
        const float inv = 1.f / (float)NN;
        float mu = s * inv;
        float var = s2 * inv - mu * mu;
        float scale = gm[c] * rsqrtf(var + 1e-5f);
        sc[c] = scale;
        sh[c] = bt[c] - mu * scale;
    }
    __syncthreads();
    const int chunk = (NN + gridDim.x - 1) / gridDim.x;
    const int r0 = blockIdx.x * chunk;
    const int r1 = imin(NN, r0 + chunk);
    for (int i = r0 * C + threadIdx.x; i < r1 * C; i += 256) {
        const int c = i % C;
        float v = fmaxf(pre[i] * sc[c] + sh[c], 0.f);
        act[i] = f2bf(v);
    }
}

extern "C" void kernel_launch(void* const* d_in, const int* in_sizes, int n_in,
                              void* d_out, int out_size, void* d_ws, size_t ws_size,
                              hipStream_t stream) {
    const void* x    = d_in[0];
    const int*  idx  = (const int*)d_in[1];
    const void* wgt  = d_in[2];
    const void* W1   = d_in[3];
    const void* b1   = d_in[4];
    const void* g1   = d_in[5];
    const void* be1  = d_in[6];
    const void* W2   = d_in[7];
    const void* b2   = d_in[8];
    const void* g2   = d_in[9];
    const void* be2  = d_in[10];
    const void* W3   = d_in[11];
    const void* b3   = d_in[12];
    const void* g3   = d_in[13];
    const void* be3  = d_in[14];
    const void* Wout = d_in[15];
    const void* bout = d_in[16];

    char* ws = (char*)d_ws;
    size_t off = 0;
    auto alloc = [&](size_t bytes) {
        off = (off + 255) & ~(size_t)255;
        size_t o = off; off += bytes; return o;
    };
    const size_t o_flag = alloc(4);
    const size_t o_xc   = alloc((size_t)NN * 3 * 2);
    const size_t o_wgtc = alloc((size_t)NN * 75 * 4);
    const size_t o_W1c  = alloc(64 * 80 * 2);
    const size_t o_Wt2  = alloc((size_t)200 * 64 * 8 * 2);
    const size_t o_Wt3  = alloc((size_t)200 * 128 * 8 * 2);
    const size_t o_Wt4  = alloc((size_t)400 * 64 * 8 * 2);
    const size_t o_bias = alloc(1024 * 4);
    const size_t o_pre  = alloc((size_t)NN * 128 * 4);
    const size_t o_actA = alloc((size_t)NN * 128 * 2);
    const size_t o_actB = alloc((size_t)NN * 64 * 2);
    const size_t o_part = alloc((size_t)64 * 2 * 128 * 4);
    if (ws_size < off) return;

    int* flag = (int*)(ws + o_flag);
    unsigned short* xc  = (unsigned short*)(ws + o_xc);
    float* wgtc = (float*)(ws + o_wgtc);
    unsigned short* W1c = (unsigned short*)(ws + o_W1c);
    unsigned short* Wt2 = (unsigned short*)(ws + o_Wt2);
    unsigned short* Wt3 = (unsigned short*)(ws + o_Wt3);
    unsigned short* Wt4 = (unsigned short*)(ws + o_Wt4);
    float* biasc = (float*)(ws + o_bias);
    float* pre  = (float*)(ws + o_pre);
    unsigned short* actA = (unsigned short*)(ws + o_actA);
    unsigned short* actB = (unsigned short*)(ws + o_actB);
    float* part = (float*)(ws + o_part);

    detect_k<<<1, 64, 0, stream>>>(wgt, flag);

    Tab t;
    t.s[0]  = { x,    xc,   NN * 3,         NN * 3,  0, 0, 0, 0 };
    t.s[1]  = { wgt,  wgtc, NN * 75,        NN * 75, 1, 0, 0, 0 };
    t.s[2]  = { W1,   W1c,  64 * 80,        64 * 80, 2, 0, 0, 0 };
    t.s[3]  = { W2,   Wt2,  200 * 64 * 8,   0,       3, 1600, 64, 64 };
    t.s[4]  = { W3,   Wt3,  200 * 128 * 8,  0,       3, 1600, 128, 128 };
    t.s[5]  = { Wout, Wt4,  400 * 64 * 8,   0,       3, 3200, 36, 64 };
    t.s[6]  = { b1,   biasc + 0,   64, 64, 1, 0, 0, 0 };
    t.s[7]  = { g1,   biasc + 64,  64, 64, 1, 0, 0, 0 };
    t.s[8]  = { be1,  biasc + 128, 64, 64, 1, 0, 0, 0 };
    t.s[9]  = { b2,   biasc + 192, 64, 64, 1, 0, 0, 0 };
    t.s[10] = { g2,   biasc + 256, 64, 64, 1, 0, 0, 0 };
    t.s[11] = { be2,  biasc + 320, 64, 64, 1, 0, 0, 0 };
    t.s[12] = { b3,   biasc + 384, 128, 128, 1, 0, 0, 0 };
    t.s[13] = { g3,   biasc + 512, 128, 128, 1, 0, 0, 0 };
    t.s[14] = { be3,  biasc + 640, 128, 128, 1, 0, 0, 0 };
    t.s[15] = { bout, biasc + 768, 36, 36, 1, 0, 0, 0 };
    canon_k<<<dim3(768, 16), 256, 0, stream>>>(t, flag);

    dim3 B(256);
    // layer 1: 3 -> 64 (VALU, K=80)
    conv_k<3, 64, 64, 16><<<641, B, 0, stream>>>(xc, idx, wgtc, W1c, biasc + 0, pre);
    stats_k<64><<<64, B, 0, stream>>>(pre, part);
    bn_k<64><<<128, B, 0, stream>>>(pre, part, biasc + 64, biasc + 128, actA);
    // layer 2: 64 -> 64 (DMA + deduped interp, ring-4)
    convdma2_k<64, 64, 64, 4, false><<<641, B, 0, stream>>>(
        actA, idx, wgtc, Wt2, biasc + 192, pre, nullptr, flag);
    stats_k<64><<<64, B, 0, stream>>>(pre, part);
    bn_k<64><<<128, B, 0, stream>>>(pre, part, biasc + 256, biasc + 320, actB);
    // layer 3: 64 -> 128 (ring-4)
    convdma2_k<64, 128, 128, 4, false><<<641, B, 0, stream>>>(
        actB, idx, wgtc, Wt3, biasc + 384, pre, nullptr, flag);
    stats_k<128><<<64, B, 0, stream>>>(pre, part);
    bn_k<128><<<128, B, 0, stream>>>(pre, part, biasc + 512, biasc + 640, actA);
    // layer 4: 128 -> 36 (COUTP=64 padded, ring-2), direct to d_out
    convdma2_k<128, 64, 36, 2, true><<<641, B, 0, stream>>>(
        actA, idx, wgtc, Wt4, biasc + 768, nullptr, d_out, flag);
}